// Round 5
// baseline (630.057 us; speedup 1.0000x reference)
//
#include <hip/hip_runtime.h>
#include <cmath>

typedef unsigned short u16;
typedef __attribute__((ext_vector_type(8))) __bf16 bf16x8;
typedef __attribute__((ext_vector_type(4))) float f32x4;

constexpr int Bb = 2, Tt = 8, Dc = 128, PIX = 4096; // b=2, c=128, 64x64 imgs

__device__ inline u16 f2bf(float f) {
    unsigned u = __builtin_bit_cast(unsigned, f);
    u += 0x7fffu + ((u >> 16) & 1u);
    return (u16)(u >> 16);
}
__device__ inline float bf2f(u16 h) {
    unsigned u = ((unsigned)h) << 16;
    return __builtin_bit_cast(float, u);
}

// ---------------------------------------------------------------------------
// Register-direct bf16 NT MFMA core: C(128x128) = A(128xK) * B(128xK)^T.
// No LDS, no barriers: each wave loads its own fragments from L2 (NT rows are
// 16B-contiguous per lane), 2-chunk software pipeline so chunk k+1's 8 loads
// overlap chunk k's 16 MFMAs. Replaces the double-barrier LDS core that
// measured MfmaUtil 8% at 1 wave/SIMD (vmcnt(0) drain serialized everything).
// kChunks must be even.
// ---------------------------------------------------------------------------
__device__ inline void mfma_nt_reg(const u16* __restrict__ A, int ldkA,
                                   const u16* __restrict__ B, int ldkB,
                                   int kChunks, int wave, int lane,
                                   f32x4 (&acc)[4][4])
{
    const int wm = (wave >> 1) * 64, wn = (wave & 1) * 64;
    const int fr = lane & 15;
    const int kq = (lane >> 4) * 8;
    const u16* Ap = A + (size_t)(wm + fr) * ldkA + kq;
    const u16* Bp = B + (size_t)(wn + fr) * ldkB + kq;
    bf16x8 a0[4], b0[4], a1[4], b1[4];
#pragma unroll
    for (int i = 0; i < 4; ++i) {
        a0[i] = *(const bf16x8*)(Ap + (size_t)(i * 16) * ldkA);
        b0[i] = *(const bf16x8*)(Bp + (size_t)(i * 16) * ldkB);
    }
    for (int kb = 0; kb < kChunks; kb += 2) {
#pragma unroll
        for (int i = 0; i < 4; ++i) {
            a1[i] = *(const bf16x8*)(Ap + (size_t)(i * 16) * ldkA + (kb + 1) * 32);
            b1[i] = *(const bf16x8*)(Bp + (size_t)(i * 16) * ldkB + (kb + 1) * 32);
        }
#pragma unroll
        for (int i = 0; i < 4; ++i)
#pragma unroll
            for (int j = 0; j < 4; ++j)
                acc[i][j] = __builtin_amdgcn_mfma_f32_16x16x32_bf16(a0[i], b0[j], acc[i][j], 0, 0, 0);
        if (kb + 2 < kChunks) {
#pragma unroll
            for (int i = 0; i < 4; ++i) {
                a0[i] = *(const bf16x8*)(Ap + (size_t)(i * 16) * ldkA + (kb + 2) * 32);
                b0[i] = *(const bf16x8*)(Bp + (size_t)(i * 16) * ldkB + (kb + 2) * 32);
            }
        }
#pragma unroll
        for (int i = 0; i < 4; ++i)
#pragma unroll
            for (int j = 0; j < 4; ++j)
                acc[i][j] = __builtin_amdgcn_mfma_f32_16x16x32_bf16(a1[i], b1[j], acc[i][j], 0, 0, 0);
    }
}

// ---------------------------------------------------------------------------
// Weight prep: Wqkv[3*128][128] bf16 stacked; WoT[tap][cout][cin] bf16.
// ---------------------------------------------------------------------------
__global__ void k_prep(const float* __restrict__ wq, const float* __restrict__ wk,
                       const float* __restrict__ wv, const float* __restrict__ wo,
                       u16* __restrict__ Wqkv, u16* __restrict__ WoT)
{
    int idx = blockIdx.x * 256 + threadIdx.x;
    if (idx < 49152) {
        const float* w = idx < 16384 ? wq : (idx < 32768 ? wk : wv);
        Wqkv[idx] = f2bf(w[idx & 16383]);
    }
    int j = idx - 49152;
    if (j >= 0 && j < 147456) {
        int tap = j / 16384, rem = j % 16384;  // rem = cout*128+cin
        WoT[j] = f2bf(wo[(size_t)rem * 9 + tap]);
    }
}

// ---------------------------------------------------------------------------
// Xt[n][pix][cin] bf16 from x[n][cin][pix] fp32 (LDS transpose, 64-pix tiles)
// ---------------------------------------------------------------------------
__global__ __launch_bounds__(256) void k_xt(const float* __restrict__ x, u16* __restrict__ Xt)
{
    __shared__ float ls[128 * 65];
    const int n = blockIdx.y, pix0 = blockIdx.x * 64;
#pragma unroll
    for (int rep = 0; rep < 32; ++rep) {
        int idx = rep * 256 + threadIdx.x;
        int cin = idx >> 6, p = idx & 63;
        ls[cin * 65 + p] = x[((size_t)n * Dc + cin) * PIX + pix0 + p];
    }
    __syncthreads();
#pragma unroll
    for (int rep = 0; rep < 32; ++rep) {
        int idx = rep * 256 + threadIdx.x;
        int p = idx >> 7, cin = idx & 127;
        Xt[((size_t)n * PIX + pix0 + p) * Dc + cin] = f2bf(ls[cin * 65 + p]);
    }
}

// ---------------------------------------------------------------------------
// Fused QKV: C[384][4096] = Wqkv * Xt^T per image; bf16 out + bias, routed.
// grid (32 pixtiles, 3 Mtiles, 16 imgs)
// ---------------------------------------------------------------------------
__global__ __launch_bounds__(256) void k_qkv_mfma(const u16* __restrict__ Wqkv,
                                                  const u16* __restrict__ Xt,
                                                  const float* __restrict__ bq,
                                                  const float* __restrict__ bk,
                                                  const float* __restrict__ bv,
                                                  u16* __restrict__ q_bf,
                                                  u16* __restrict__ k_bf,
                                                  u16* __restrict__ v_bf)
{
    const int tid = threadIdx.x, wave = tid >> 6, lane = tid & 63;
    const int mt = blockIdx.y, n = blockIdx.z, px0 = blockIdx.x * 128;
    f32x4 acc[4][4];
#pragma unroll
    for (int i = 0; i < 4; ++i)
#pragma unroll
        for (int j = 0; j < 4; ++j) acc[i][j] = (f32x4){0.f, 0.f, 0.f, 0.f};
    mfma_nt_reg(Wqkv + (size_t)mt * 128 * 128, 128,
                Xt + ((size_t)n * PIX + px0) * 128, 128, 4, wave, lane, acc);
    const int wm = (wave >> 1) * 64, wn = (wave & 1) * 64;
    const int rb = (lane >> 4) * 4, cb = lane & 15;
#pragma unroll
    for (int i = 0; i < 4; ++i)
#pragma unroll
        for (int reg = 0; reg < 4; ++reg) {
            int gmg = mt * 128 + wm + i * 16 + rb + reg;     // stacked cout 0..383
            int sel = gmg >> 7, c = gmg & 127;
            float bias = (sel == 0 ? bq : sel == 1 ? bk : bv)[c];
            u16* dst = (sel == 0 ? q_bf : sel == 1 ? k_bf : v_bf);
#pragma unroll
            for (int j = 0; j < 4; ++j) {
                int pix = px0 + wn + j * 16 + cb;
                dst[((size_t)n * Dc + c) * PIX + pix] = f2bf(acc[i][j][reg] + bias);
            }
        }
}

// ---------------------------------------------------------------------------
// depthwise 3x3 add into bf16 v_all. grid (16, 128, 16)
// ---------------------------------------------------------------------------
__global__ __launch_bounds__(256) void k_vdw(const float* __restrict__ X,
                                             const float* __restrict__ wvle,
                                             const float* __restrict__ bvle,
                                             u16* __restrict__ v_bf)
{
    const int n = blockIdx.z, c = blockIdx.y;
    const int p = blockIdx.x * 256 + threadIdx.x;
    const int y = p >> 6, x = p & 63;
    const float* xp = X + ((size_t)n * Dc + c) * PIX;
    const float* w  = wvle + c * 9;
    float s = bvle[c];
#pragma unroll
    for (int ky = 0; ky < 3; ++ky) {
        int yy = y + ky - 1;
        if (yy < 0 || yy >= 64) continue;
#pragma unroll
        for (int kx = 0; kx < 3; ++kx) {
            int xx = x + kx - 1;
            if (xx < 0 || xx >= 64) continue;
            s += w[ky * 3 + kx] * xp[yy * 64 + xx];
        }
    }
    size_t idx = ((size_t)n * Dc + c) * PIX + p;
    v_bf[idx] = f2bf(bf2f(v_bf[idx]) + s);
}

// ---------------------------------------------------------------------------
// Depth path, kernel 1: d1[n][c][128][128] = relu(conv(dm, wd1, s2, p1)) bf16.
// ---------------------------------------------------------------------------
__global__ __launch_bounds__(256) void k_d1(const float* __restrict__ dm,
                                            const float* __restrict__ wd1,
                                            const float* __restrict__ bd1,
                                            u16* __restrict__ d1b)
{
    __shared__ float ls[17 * 132];
    const int n = blockIdx.y;
    const int yt = blockIdx.x >> 1, xh = blockIdx.x & 1;
    const int Y0 = yt * 8;
    const int tid = threadIdx.x;
    const float* dmp = dm + (size_t)n * 65536;
    for (int idx = tid; idx < 17 * 132; idx += 256) {
        int row = idx / 132, cl = idx % 132;
        int gr = 2 * Y0 - 1 + row;
        int gc = 128 * xh - 1 + cl;
        float v = 0.f;
        if (gr >= 0 && gr < 256 && gc >= 0 && gc < 256 && cl < 129) v = dmp[gr * 256 + gc];
        ls[idx] = v;
    }
    __syncthreads();
    const int Xl = tid & 63;
    const int Yl0 = tid >> 6;                 // rows Yl0 and Yl0+4
    float in0[9], in1[9];
#pragma unroll
    for (int jy = 0; jy < 3; ++jy)
#pragma unroll
        for (int jx = 0; jx < 3; ++jx) {
            in0[jy * 3 + jx] = ls[(2 * Yl0 + jy) * 132 + 2 * Xl + jx];
            in1[jy * 3 + jx] = ls[(2 * (Yl0 + 4) + jy) * 132 + 2 * Xl + jx];
        }
    const int X = 64 * xh + Xl;
    u16* outbase = d1b + (size_t)n * Dc * 16384 + (size_t)Y0 * 128 + X;
    for (int c = 0; c < 128; ++c) {
        const float* w1 = wd1 + c * 9;        // uniform -> s_load
        float a0 = bd1[c], a1 = a0;
#pragma unroll
        for (int t = 0; t < 9; ++t) { a0 += w1[t] * in0[t]; a1 += w1[t] * in1[t]; }
        u16* ob = outbase + (size_t)c * 16384;
        ob[(size_t)Yl0 * 128]       = f2bf(fmaxf(a0, 0.f));
        ob[(size_t)(Yl0 + 4) * 128] = f2bf(fmaxf(a1, 0.f));
    }
}

// ---------------------------------------------------------------------------
// Depth path, kernel 2: partial conv2 over 16-channel groups.
// ---------------------------------------------------------------------------
__global__ __launch_bounds__(256) void k_d2p(const u16* __restrict__ d1b,
                                             const float* __restrict__ wd2,
                                             float* __restrict__ part)
{
    __shared__ u16 ls[33 * 136];              // payload at cl 8..135, zero at cl 7
    const int yt = blockIdx.x, n = blockIdx.y, cg = blockIdx.z;
    const int tid = threadIdx.x;
    const int y0 = yt * 16;
    if (tid < 33) ls[tid * 136 + 7] = 0;
    const int x = tid & 63;
    const int yl0 = (tid >> 6) * 4;
    float acc[4] = {0.f, 0.f, 0.f, 0.f};
    for (int c = 0; c < 16; ++c) {
        const u16* src = d1b + ((size_t)n * Dc + cg * 16 + c) * 16384;
        __syncthreads();
        for (int idx = tid; idx < 33 * 16; idx += 256) {
            int row = idx >> 4, s = idx & 15;
            int gr = 2 * y0 - 1 + row;
            uint4 v = make_uint4(0, 0, 0, 0);
            if (gr >= 0 && gr < 128) v = *(const uint4*)(src + gr * 128 + s * 8);
            *(uint4*)&ls[row * 136 + 8 + s * 8] = v;
        }
        __syncthreads();
        const float* w2 = wd2 + (cg * 16 + c) * 9;   // uniform -> s_load
        float w[9];
#pragma unroll
        for (int t = 0; t < 9; ++t) w[t] = w2[t];
#pragma unroll
        for (int r = 0; r < 4; ++r) {
            int yl = yl0 + r;
#pragma unroll
            for (int ky = 0; ky < 3; ++ky) {
                const u16* rp = &ls[(2 * yl + ky) * 136 + 2 * x + 7];
                float v0 = bf2f(rp[0]);
                unsigned pr = *(const unsigned*)(rp + 1);
                float v1 = bf2f((u16)(pr & 0xffffu));
                float v2 = bf2f((u16)(pr >> 16));
                acc[r] += w[ky * 3 + 0] * v0 + w[ky * 3 + 1] * v1 + w[ky * 3 + 2] * v2;
            }
        }
    }
    float* pp = part + ((size_t)cg * 16 + n) * PIX;
#pragma unroll
    for (int r = 0; r < 4; ++r)
        pp[(y0 + yl0 + r) * 64 + x] = acc[r];
}

// Depth path, kernel 3: dep = relu(sum_cg part + bd2). grid (256)
__global__ void k_dfin(const float* __restrict__ part, const float* __restrict__ bd2,
                       float* __restrict__ dep)
{
    int idx = blockIdx.x * 256 + threadIdx.x;
    float s = bd2[0];
#pragma unroll
    for (int cg = 0; cg < 8; ++cg) s += part[(size_t)cg * 65536 + idx];
    dep[idx] = fmaxf(s, 0.f);
}

// ---------------------------------------------------------------------------
// Wave-parallel per-token stats (min/max/mask butterfly, exact median rank).
// ---------------------------------------------------------------------------
template<int PS>
__global__ __launch_bounds__(256) void k_stats2(const float* __restrict__ mI,
                                                const float* __restrict__ dep,
                                                float* __restrict__ maskf,
                                                float* __restrict__ smed,
                                                float* __restrict__ smaxA,
                                                float* __restrict__ sminA,
                                                int outn, int L)
{
    constexpr int HW = PS * PS;              // 16 or 64
    constexpr int TPB = 256 / HW;
    const int tok = blockIdx.x * TPB + threadIdx.x / HW;
    const int el  = threadIdx.x % HW;
    if (tok >= Bb * L) return;
    const int bi = tok / L, l = tok % L;
    const int ti = l / (outn * outn); const int rem = l % (outn * outn);
    const int oh = rem / outn, ow = rem % outn;
    const int n = bi * Tt + ti;
    const int py = el / PS, px = el % PS;
    const size_t off = (size_t)n * PIX + (size_t)(oh * PS + py) * 64 + ow * PS + px;
    const float mv = mI[off];
    const float dv = dep[off];
    float msum = mv, vmin = dv, vmax = dv;
#pragma unroll
    for (int o = HW / 2; o > 0; o >>= 1) {
        msum += __shfl_xor(msum, o);
        vmin = fminf(vmin, __shfl_xor(vmin, o));
        vmax = fmaxf(vmax, __shfl_xor(vmax, o));
    }
    const int gbase = (threadIdx.x & 63) & ~(HW - 1);
    int cl = 0, ce = 0;
#pragma unroll
    for (int b2 = 0; b2 < HW; ++b2) {
        float vb = __shfl(dv, gbase + b2);
        cl += (vb < dv);
        ce += (vb == dv);
    }
    constexpr int kk = (HW - 1) / 2;
    if (el == 0) {
        maskf[tok] = (msum / (float)HW > 0.5f) ? 1.f : 0.f;
        smaxA[tok] = 1.f / (1.f + __expf(-vmax));
        sminA[tok] = 1.f / (1.f + __expf(-vmin));
    }
    if (cl <= kk && kk < cl + ce)
        smed[tok] = 1.f / (1.f + __expf(-dv));
}

// ---------------------------------------------------------------------------
// Patch-extract bf16 -> bf16 [bi][l][f], 4 elements (=4 px) per thread.
// ---------------------------------------------------------------------------
__global__ void k_patch_bf(const u16* __restrict__ src, u16* __restrict__ dst,
                           int ps, int outn, int L, int F, int cbase)
{
    size_t idx = (size_t)blockIdx.x * 256 + threadIdx.x;
    size_t total = (size_t)Bb * L * F / 4;
    if (idx >= total) return;
    int f0 = (int)((idx * 4) % F);
    size_t t2 = (idx * 4) / F;
    int l = (int)(t2 % L);
    int bi = (int)(t2 / L);
    int hw = ps * ps;
    int ti = l / (outn * outn); int rem = l % (outn * outn);
    int oh = rem / outn, ow = rem % outn;
    int c = f0 / hw, r = f0 % hw;
    int py = r / ps, px = r % ps;
    int n = bi * Tt + ti;
    size_t si = ((size_t)n * Dc + cbase + c) * PIX + (oh * ps + py) * 64 + ow * ps + px;
    *(uint2*)&dst[((size_t)bi * L + l) * F + f0] = *(const uint2*)&src[si];
}

// V transposed patch: Vt[bi][f][l] bf16. 4 consecutive l per thread.
__global__ void k_patchT(const u16* __restrict__ v_bf, u16* __restrict__ Vt,
                         int ps, int outn, int L, int F, int cbase)
{
    size_t idx = (size_t)blockIdx.x * 256 + threadIdx.x;
    size_t total = (size_t)Bb * F * L / 4;
    if (idx >= total) return;
    int l0 = (int)((idx * 4) % L);
    size_t t2 = (idx * 4) / L;
    int f = (int)(t2 % F);
    int bi = (int)(t2 / F);
    int hw = ps * ps;
    int c = cbase + f / hw, r = f % hw;
    int py = r / ps, px = r % ps;
    int ti = l0 / (outn * outn); int rem = l0 % (outn * outn);
    int oh = rem / outn, ow0 = rem % outn;
    size_t base = ((size_t)(bi * Tt + ti) * Dc + c) * PIX + (oh * ps + py) * 64 + px;
    u16 out4[4];
#pragma unroll
    for (int e = 0; e < 4; ++e) out4[e] = v_bf[base + (size_t)(ow0 + e) * ps];
    *(uint2*)&Vt[((size_t)bi * F + f) * L + l0] = *(uint2*)out4;
}

// ---------------------------------------------------------------------------
// S = scale * Q K^T (bf16 MFMA, register-direct), fp32 out. Split-K writes
// DISJOINT partial buffers; softmax sums them.
// ---------------------------------------------------------------------------
__global__ __launch_bounds__(256) void k_qkT_mfma(const u16* __restrict__ Qp,
                                                  const u16* __restrict__ Kp,
                                                  float* __restrict__ S,
                                                  int L, int F, int ksplit, float scale)
{
    const int tid = threadIdx.x, wave = tid >> 6, lane = tid & 63;
    const int bi = blockIdx.z / ksplit, ks = blockIdx.z % ksplit;
    const int kf = F / ksplit;
    f32x4 acc[4][4];
#pragma unroll
    for (int i = 0; i < 4; ++i)
#pragma unroll
        for (int j = 0; j < 4; ++j) acc[i][j] = (f32x4){0.f, 0.f, 0.f, 0.f};
    mfma_nt_reg(Qp + (size_t)bi * L * F + (size_t)blockIdx.y * 128 * F + (size_t)ks * kf, F,
                Kp + (size_t)bi * L * F + (size_t)blockIdx.x * 128 * F + (size_t)ks * kf, F,
                kf / 32, wave, lane, acc);
    const int wm = (wave >> 1) * 64, wn = (wave & 1) * 64;
    const int rb = (lane >> 4) * 4, cb = lane & 15;
    float* Cp = S + ((size_t)ks * Bb + bi) * L * L;
#pragma unroll
    for (int i = 0; i < 4; ++i)
#pragma unroll
        for (int reg = 0; reg < 4; ++reg) {
            int gm = blockIdx.y * 128 + wm + i * 16 + rb + reg;
#pragma unroll
            for (int j = 0; j < 4; ++j) {
                int gn = blockIdx.x * 128 + wn + j * 16 + cb;
                Cp[(size_t)gm * L + gn] = acc[i][j][reg] * scale;
            }
        }
}

// ---------------------------------------------------------------------------
// 3-head softmax (sums NSPLIT partial S buffers), combined probs -> bf16 Pb.
// ---------------------------------------------------------------------------
__device__ inline float blockMax(float v, float* sh) {
#pragma unroll
    for (int o = 32; o > 0; o >>= 1) v = fmaxf(v, __shfl_down(v, o));
    __syncthreads();
    if ((threadIdx.x & 63) == 0) sh[threadIdx.x >> 6] = v;
    __syncthreads();
    return fmaxf(fmaxf(sh[0], sh[1]), fmaxf(sh[2], sh[3]));
}
__device__ inline float blockSum(float v, float* sh) {
#pragma unroll
    for (int o = 32; o > 0; o >>= 1) v += __shfl_down(v, o);
    __syncthreads();
    if ((threadIdx.x & 63) == 0) sh[threadIdx.x >> 6] = v;
    __syncthreads();
    return sh[0] + sh[1] + sh[2] + sh[3];
}

template<int NV, int NSPLIT>
__global__ __launch_bounds__(256) void k_softmax(const float* __restrict__ S,
                                                 u16* __restrict__ Pb,
                                                 const float* __restrict__ maskf,
                                                 const float* __restrict__ smed,
                                                 const float* __restrict__ smaxA,
                                                 const float* __restrict__ sminA,
                                                 int L)
{
    __shared__ float sred[4];
    const int bi = blockIdx.y, q = blockIdx.x;
    const size_t pstr = (size_t)Bb * L * L;
    const float* row = S + (size_t)bi * L * L + (size_t)q * L;
    u16* prow = Pb + (size_t)bi * L * L + (size_t)q * L;
    const float* mk  = maskf + bi * L;
    const float* s0p = smed  + bi * L;
    const float* s1p = smaxA + bi * L;
    const float* s2p = sminA + bi * L;
    const int tid = threadIdx.x;
    float a0[NV], a1[NV], a2[NV];
    float m0 = -3.4e38f, m1 = -3.4e38f, m2 = -3.4e38f;
#pragma unroll
    for (int e = 0; e < NV; ++e) {
        int k = e * 256 + tid;
        float sv = row[k];
#pragma unroll
        for (int s2 = 1; s2 < NSPLIT; ++s2) sv += row[(size_t)s2 * pstr + k];
        bool msk = mk[k] > 0.5f;
        float v0 = msk ? -1e9f : sv * s0p[k];
        float v1 = msk ? -1e9f : sv * s1p[k];
        float v2 = msk ? -1e9f : sv * s2p[k];
        a0[e] = v0; a1[e] = v1; a2[e] = v2;
        m0 = fmaxf(m0, v0); m1 = fmaxf(m1, v1); m2 = fmaxf(m2, v2);
    }
    m0 = blockMax(m0, sred); m1 = blockMax(m1, sred); m2 = blockMax(m2, sred);
    float l0 = 0.f, l1 = 0.f, l2 = 0.f;
#pragma unroll
    for (int e = 0; e < NV; ++e) {
        a0[e] = __expf(a0[e] - m0); l0 += a0[e];
        a1[e] = __expf(a1[e] - m1); l1 += a1[e];
        a2[e] = __expf(a2[e] - m2); l2 += a2[e];
    }
    l0 = blockSum(l0, sred); l1 = blockSum(l1, sred); l2 = blockSum(l2, sred);
    float c0 = 1.f / (3.f * l0), c1 = 1.f / (3.f * l1), c2 = 1.f / (3.f * l2);
#pragma unroll
    for (int e = 0; e < NV; ++e)
        prow[e * 256 + tid] = f2bf(a0[e] * c0 + a1[e] * c1 + a2[e] * c2);
}

// ---------------------------------------------------------------------------
// Y = P @ V (register-direct, split-K=2). Partials written as COALESCED bf16
// rows Yp[ks][bi][l][f]; the NHWC scatter moved to k_unpatch (memory pass).
// grid (F/128, L/128, Bb*2)
// ---------------------------------------------------------------------------
__global__ __launch_bounds__(256) void k_pv_mfma(const u16* __restrict__ Pb,
                                                 const u16* __restrict__ Vt,
                                                 u16* __restrict__ Yp,
                                                 int L, int F)
{
    const int tid = threadIdx.x, wave = tid >> 6, lane = tid & 63;
    const int bi = blockIdx.z >> 1, ks = blockIdx.z & 1;
    const int kf = L / 2;
    f32x4 acc[4][4];
#pragma unroll
    for (int i = 0; i < 4; ++i)
#pragma unroll
        for (int j = 0; j < 4; ++j) acc[i][j] = (f32x4){0.f, 0.f, 0.f, 0.f};
    mfma_nt_reg(Pb + (size_t)bi * L * L + (size_t)blockIdx.y * 128 * L + (size_t)ks * kf, L,
                Vt + (size_t)bi * F * L + (size_t)blockIdx.x * 128 * L + (size_t)ks * kf, L,
                kf / 32, wave, lane, acc);
    const int wm = (wave >> 1) * 64, wn = (wave & 1) * 64;
    const int rb = (lane >> 4) * 4, cb = lane & 15;
    u16* Cp = Yp + ((size_t)(ks * Bb + bi) * L) * F;
#pragma unroll
    for (int i = 0; i < 4; ++i)
#pragma unroll
        for (int reg = 0; reg < 4; ++reg) {
            int gm = blockIdx.y * 128 + wm + i * 16 + rb + reg;
#pragma unroll
            for (int j = 0; j < 4; ++j) {
                int gn = blockIdx.x * 128 + wn + j * 16 + cb;
                Cp[(size_t)gm * F + gn] = f2bf(acc[i][j][reg]);
            }
        }
}

// ---------------------------------------------------------------------------
// Sum 2 Yp split-partials + scatter to catbT[pix][cin]. Coalesced 8B reads;
// 4 consecutive f share one channel -> 4 u16 stores at pix-stride.
// ---------------------------------------------------------------------------
__global__ void k_unpatch(const u16* __restrict__ Yp, u16* __restrict__ catbT,
                          int ps, int outn, int L, int F, int cbase)
{
    size_t idx = (size_t)blockIdx.x * 256 + threadIdx.x;
    size_t total = (size_t)Bb * L * F / 4;
    if (idx >= total) return;
    const size_t pstr = (size_t)Bb * L * F;
    int f0 = (int)((idx * 4) % F);
    size_t t2 = (idx * 4) / F;
    int l = (int)(t2 % L);
    int bi = (int)(t2 / L);
    size_t off = ((size_t)bi * L + l) * F + f0;
    uint2 u0 = *(const uint2*)&Yp[off];
    uint2 u1 = *(const uint2*)&Yp[pstr + off];
    float s[4];
    s[0] = bf2f((u16)(u0.x & 0xffffu)) + bf2f((u16)(u1.x & 0xffffu));
    s[1] = bf2f((u16)(u0.x >> 16))     + bf2f((u16)(u1.x >> 16));
    s[2] = bf2f((u16)(u0.y & 0xffffu)) + bf2f((u16)(u1.y & 0xffffu));
    s[3] = bf2f((u16)(u0.y >> 16))     + bf2f((u16)(u1.y >> 16));
    int hw = ps * ps;
    int c = cbase + f0 / hw, r0 = f0 % hw;
    int ti = l / (outn * outn); int rem = l % (outn * outn);
    int oh = rem / outn, ow = rem % outn;
    int n = bi * Tt + ti;
    int py = r0 / ps, px = r0 % ps;   // r0 4-aligned, ps in {4,8} -> same row, 4 consecutive px
    size_t base = ((size_t)n * PIX + (size_t)(oh * ps + py) * 64 + ow * ps + px) * Dc + c;
#pragma unroll
    for (int e = 0; e < 4; ++e)
        catbT[base + (size_t)e * Dc] = f2bf(s[e]);
}

// ---------------------------------------------------------------------------
// Output conv 3x3 as 9-tap implicit NT GEMM, register-direct with per-lane
// OOB predication (no LDS, no barriers). grid (512 pixel tiles)
// ---------------------------------------------------------------------------
__global__ __launch_bounds__(256) void k_conv_mfma(const u16* __restrict__ catbT,
                                                   const u16* __restrict__ WoT,
                                                   const float* __restrict__ bo,
                                                   float* __restrict__ outp)
{
    const int tid = threadIdx.x, wave = tid >> 6, lane = tid & 63;
    const int pix0 = blockIdx.x * 128;
    const int wm = (wave >> 1) * 64, wn = (wave & 1) * 64;
    const int fr = lane & 15, kq = (lane >> 4) * 8;
    f32x4 acc[4][4];
#pragma unroll
    for (int i = 0; i < 4; ++i)
#pragma unroll
        for (int j = 0; j < 4; ++j) acc[i][j] = (f32x4){0.f, 0.f, 0.f, 0.f};
    for (int tap = 0; tap < 9; ++tap) {
        const int dy = tap / 3 - 1, dx = tap % 3 - 1;
        const u16* arow[4]; bool aok[4];
#pragma unroll
        for (int i = 0; i < 4; ++i) {
            int pg = pix0 + wm + i * 16 + fr;
            int n = pg >> 12, p = pg & 4095;
            int y = (p >> 6) + dy, xx = (p & 63) + dx;
            aok[i] = (y >= 0 && y < 64 && xx >= 0 && xx < 64);
            int pix = aok[i] ? (y * 64 + xx) : 0;
            arow[i] = catbT + (((size_t)(n << 12) + pix) << 7) + kq;
        }
        const u16* bbase = WoT + tap * 16384 + (size_t)fr * 128 + kq;
#pragma unroll
        for (int kb = 0; kb < 4; ++kb) {
            bf16x8 av[4], bv[4];
#pragma unroll
            for (int i = 0; i < 4; ++i) {
                uint4 t = *(const uint4*)(arow[i] + kb * 32);
                if (!aok[i]) t = make_uint4(0, 0, 0, 0);
                av[i] = __builtin_bit_cast(bf16x8, t);
            }
#pragma unroll
            for (int j = 0; j < 4; ++j)
                bv[j] = *(const bf16x8*)(bbase + (size_t)(wn + j * 16) * 128 + kb * 32);
#pragma unroll
            for (int i = 0; i < 4; ++i)
#pragma unroll
                for (int j = 0; j < 4; ++j)
                    acc[i][j] = __builtin_amdgcn_mfma_f32_16x16x32_bf16(av[i], bv[j], acc[i][j], 0, 0, 0);
        }
    }
    const int rb = (lane >> 4) * 4, cb = lane & 15;
#pragma unroll
    for (int i = 0; i < 4; ++i)
#pragma unroll
        for (int reg = 0; reg < 4; ++reg) {
            int pg = pix0 + wm + i * 16 + rb + reg;
            int n = pg >> 12, p = pg & 4095;
#pragma unroll
            for (int j = 0; j < 4; ++j) {
                int cout = wn + j * 16 + cb;
                float v = acc[i][j][reg] + bo[cout];
                v = (v >= 0.f) ? v : 0.2f * v;
                outp[((size_t)n * Dc + cout) * PIX + p] = v;
            }
        }
}

// ---------------------------------------------------------------------------
extern "C" void kernel_launch(void* const* d_in, const int* in_sizes, int n_in,
                              void* d_out, int out_size, void* d_ws, size_t ws_size,
                              hipStream_t stream)
{
    (void)in_sizes; (void)n_in; (void)out_size; (void)ws_size;
    const float* x    = (const float*)d_in[0];
    const float* mI   = (const float*)d_in[1];
    const float* dmap = (const float*)d_in[2];
    const float* wq   = (const float*)d_in[3];
    const float* bq   = (const float*)d_in[4];
    const float* wk   = (const float*)d_in[5];
    const float* bk   = (const float*)d_in[6];
    const float* wv   = (const float*)d_in[7];
    const float* bv   = (const float*)d_in[8];
    const float* wvle = (const float*)d_in[9];
    const float* bvle = (const float*)d_in[10];
    const float* wd1  = (const float*)d_in[11];
    const float* bd1  = (const float*)d_in[12];
    const float* wd2  = (const float*)d_in[13];
    const float* bd2  = (const float*)d_in[14];
    const float* wo   = (const float*)d_in[15];
    const float* bo   = (const float*)d_in[16];

    // workspace layout (~162 MB)
    char* w8 = (char*)d_ws;
    u16*   q_bf  = (u16*)(w8);                    // 16 MB each
    u16*   k_bf  = (u16*)(w8 + 0x1000000);
    u16*   v_bf  = (u16*)(w8 + 0x2000000);
    u16*   Xt    = (u16*)(w8 + 0x3000000);
    u16*   catbT = (u16*)(w8 + 0x4000000);
    u16*   Qp    = (u16*)(w8 + 0x5000000);        // 8 MB each
    u16*   Kp    = (u16*)(w8 + 0x5800000);
    u16*   Vt    = (u16*)(w8 + 0x6000000);
    float* Sb    = (float*)(w8 + 0x6800000);      // 16 MB (S / 8x2MB partials)
    u16*   Yp    = (u16*)(w8 + 0x7800000);        // 16 MB (2 pv split-partials; S dead by then)
    u16*   Pb    = (u16*)(w8 + 0x8800000);        // 16 MB
    // d1b (67 MB) ALIASES Qp..Pb: depth path runs strictly before the attn loop
    u16*   d1b   = (u16*)(w8 + 0x5000000);
    float* dep   = (float*)(w8 + 0x9800000);
    float* maskf = (float*)(w8 + 0x9840000);
    float* smed  = (float*)(w8 + 0x9844000);
    float* smaxA = (float*)(w8 + 0x9848000);
    float* sminA = (float*)(w8 + 0x984C000);
    u16*   Wqkv  = (u16*)(w8 + 0x9850000);
    u16*   WoT   = (u16*)(w8 + 0x9868000);
    float* part  = (float*)(w8 + 0x98C0000);      // 2 MB
    float* outp  = (float*)d_out;

    hipMemcpyAsync(outp + 8388608, dmap, (size_t)16 * 65536 * sizeof(float),
                   hipMemcpyDeviceToDevice, stream);

    dim3 blk(256);
    // depth path first (d1b aliases attention scratch)
    k_d1<<<dim3(32, 16), blk, 0, stream>>>(dmap, wd1, bd1, d1b);
    k_d2p<<<dim3(4, 16, 8), blk, 0, stream>>>(d1b, wd2, part);
    k_dfin<<<dim3(256), blk, 0, stream>>>(part, bd2, dep);

    k_prep<<<dim3(768), blk, 0, stream>>>(wq, wk, wv, wo, Wqkv, WoT);
    k_xt<<<dim3(64, 16), blk, 0, stream>>>(x, Xt);
    k_qkv_mfma<<<dim3(32, 3, 16), blk, 0, stream>>>(Wqkv, Xt, bq, bk, bv, q_bf, k_bf, v_bf);
    k_vdw<<<dim3(16, 128, 16), blk, 0, stream>>>(x, wvle, bvle, v_bf);

    for (int i = 0; i < 2; ++i) {
        const int ps = (i == 0) ? 4 : 8;
        const int outn = 64 / ps;
        const int L = Tt * outn * outn;        // 2048 / 512
        const int F = 64 * ps * ps;            // 1024 / 4096
        const int cbase = i * 64;
        const float scale = 1.0f / sqrtf((float)F);
        const int ksplit = (i == 0) ? 1 : 8;

        if (i == 0) k_stats2<4><<<dim3(Bb * L * 16 / 256), blk, 0, stream>>>(mI, dep, maskf, smed, smaxA, sminA, outn, L);
        else        k_stats2<8><<<dim3(Bb * L * 64 / 256), blk, 0, stream>>>(mI, dep, maskf, smed, smaxA, sminA, outn, L);

        const int pgrid = (int)(((size_t)Bb * L * F / 4 + 255) / 256);
        k_patch_bf<<<dim3(pgrid), blk, 0, stream>>>(q_bf, Qp, ps, outn, L, F, cbase);
        k_patch_bf<<<dim3(pgrid), blk, 0, stream>>>(k_bf, Kp, ps, outn, L, F, cbase);
        k_patchT<<<dim3(pgrid), blk, 0, stream>>>(v_bf, Vt, ps, outn, L, F, cbase);

        k_qkT_mfma<<<dim3(L / 128, L / 128, Bb * ksplit), blk, 0, stream>>>(Qp, Kp, Sb, L, F, ksplit, scale);

        if (i == 0) k_softmax<8, 1><<<dim3(L, Bb), blk, 0, stream>>>(Sb, Pb, maskf, smed, smaxA, sminA, L);
        else        k_softmax<2, 8><<<dim3(L, Bb), blk, 0, stream>>>(Sb, Pb, maskf, smed, smaxA, sminA, L);

        k_pv_mfma<<<dim3(F / 128, L / 128, Bb * 2), blk, 0, stream>>>(Pb, Vt, Yp, L, F);
        k_unpatch<<<dim3(pgrid), blk, 0, stream>>>(Yp, catbT, ps, outn, L, F, cbase);
    }

    k_conv_mfma<<<dim3(512), blk, 0, stream>>>(catbT, WoT, bo, outp);
}